// Round 1
// baseline (1185.183 us; speedup 1.0000x reference)
//
#include <hip/hip_runtime.h>
#include <cstddef>

#define T_ 1024
#define B_ 128
#define F_ 243
#define H_ 20
#define G_ 60   // 3*H
#define R_ 512  // B*POOL

// ---------------- K1: max-pool(4) + x_gates = h @ W_ih^T + b_ih ----------------
// One block per timestep t. W_ih staged in LDS (stride 244 so float4 reads are
// 16B-aligned; col 243 zero-padded). Per pass: pool 4 batch rows into LDS
// (+ store h_seq), then each wave computes the 60 gate dots for one row
// (lane = gate, full 243-dot per thread; h reads are broadcasts).
__global__ __launch_bounds__(256) void k1_pool_gates(
    const float* __restrict__ feats, const float* __restrict__ W_ih,
    const float* __restrict__ b_ih, float* __restrict__ h_seq,
    float* __restrict__ xg)
{
  __shared__ __align__(16) float wih[G_ * 244];   // 58560 B
  __shared__ __align__(16) float hb[4][244];      //  3904 B
  const int t = blockIdx.x;
  const int tid = threadIdx.x;
  const int wave = tid >> 6, lane = tid & 63;

  for (int i = tid; i < G_ * F_; i += 256) {
    int g = i / F_, f = i - g * F_;
    wih[g * 244 + f] = W_ih[i];
  }
  if (tid < G_) wih[tid * 244 + 243] = 0.f;
  if (tid < 4) hb[tid][243] = 0.f;

  float bi = (lane < G_) ? b_ih[lane] : 0.f;
  __syncthreads();

  const float* fbase = feats + (size_t)t * R_ * F_;

  for (int b0 = 0; b0 < B_; b0 += 4) {
    // pool 4 rows of 4 into hb + h_seq
    for (int i = tid; i < 4 * F_; i += 256) {
      int bb = i / F_, f = i - bb * F_;
      const float* p = fbase + (size_t)(b0 + bb) * 4 * F_ + f;
      float m = fmaxf(fmaxf(p[0], p[F_]), fmaxf(p[2 * F_], p[3 * F_]));
      hb[bb][f] = m;
      h_seq[((size_t)t * B_ + (b0 + bb)) * F_ + f] = m;
    }
    __syncthreads();
    // gate dots: wave w handles row b0+w, lane g < 60 does the full 243-dot
    if (lane < G_) {
      const int g = lane;
      float acc = 0.f;
      #pragma unroll 4
      for (int f = 0; f < 244; f += 4) {
        const float4 w4 = *(const float4*)&wih[g * 244 + f];
        const float4 a4 = *(const float4*)&hb[wave][f];
        acc += w4.x * a4.x + w4.y * a4.y + w4.z * a4.z + w4.w * a4.w;
      }
      xg[((size_t)t * B_ + (b0 + wave)) * G_ + g] = acc + bi;
    }
    __syncthreads();
  }
}

// ---------------- K2: sequential GRU scan + decoder + per-row loss ----------------
// One block per batch row b. 5 waves: wave 0 = recurrence producer (all in
// registers, e broadcast via shfl), waves 1-4 = decoder consumers working on
// step t-1 while the producer computes step t. One barrier per step, e
// published through a parity double-buffered LDS slot. x_gates / h_seq are
// prefetched 2 steps ahead with rotating scalar registers.
__global__ __launch_bounds__(320) void k2_scan(
    const float* __restrict__ e0, const float* __restrict__ W_hh,
    const float* __restrict__ b_hh, const float* __restrict__ W_dec,
    const float* __restrict__ b_dec, const float* __restrict__ h_seq,
    const float* __restrict__ xg, float* __restrict__ partials)
{
  __shared__ float ebuf[2][H_];
  __shared__ float red[8];
  const int b = blockIdx.x;
  const int tid = threadIdx.x;
  const int lane = tid & 63;
  const int wave = tid >> 6;
  float acc = 0.f;  // producers leave this 0

  if (tid < 64) {
    // ---------- producer wave ----------
    float w[H_];
    float bh = 0.f;
    if (lane < G_) {
      #pragma unroll
      for (int k = 0; k < H_; ++k) w[k] = W_hh[lane * H_ + k];
      bh = b_hh[lane];
    }
    float e[H_];
    #pragma unroll
    for (int k = 0; k < H_; ++k) e[k] = e0[b * H_ + k];

    float xv0 = (lane < G_) ? xg[((size_t)0 * B_ + b) * G_ + lane] : 0.f;
    float xv1 = (lane < G_) ? xg[((size_t)1 * B_ + b) * G_ + lane] : 0.f;

    for (int i = 0; i <= T_; ++i) {
      if (i < T_) {
        float xv2 = (i + 2 < T_ && lane < G_)
                        ? xg[((size_t)(i + 2) * B_ + b) * G_ + lane] : 0.f;
        float hg = bh;
        #pragma unroll
        for (int k = 0; k < H_; ++k) hg += w[k] * e[k];
        // gather the z / n components onto lanes 0..19
        float hg1 = __shfl(hg, lane + 20);
        float hg2 = __shfl(hg, lane + 40);
        float xz = __shfl(xv0, lane + 20);
        float xn = __shfl(xv0, lane + 40);
        float enew = 0.f;
        if (lane < H_) {
          float r = 1.f / (1.f + __expf(-(xv0 + hg)));
          float z = 1.f / (1.f + __expf(-(xz + hg1)));
          float n = tanhf(xn + r * hg2);
          enew = (1.f - z) * n + z * e[lane];
        }
        #pragma unroll
        for (int k = 0; k < H_; ++k) e[k] = __shfl(enew, k);
        if (lane < H_) ebuf[(i + 1) & 1][lane] = enew;
        xv0 = xv1;
        xv1 = xv2;
      }
      __syncthreads();
    }
  } else {
    // ---------- consumer waves (decoder + loss) ----------
    const int ct = tid - 64;
    const bool act = ct < F_;
    float wd[H_];
    float bd = 0.f;
    if (act) {
      #pragma unroll
      for (int k = 0; k < H_; ++k) wd[k] = W_dec[ct * H_ + k];
      bd = b_dec[ct];
    }
    float h0 = act ? h_seq[((size_t)0 * B_ + b) * F_ + ct] : 0.f;
    float h1 = act ? h_seq[((size_t)1 * B_ + b) * F_ + ct] : 0.f;
    __syncthreads();  // matches producer's i=0 barrier
    for (int i = 1; i <= T_; ++i) {
      const int s = i - 1;  // step being decoded, uses e_{s+1} = ebuf[i&1]
      float h2 = (s + 2 < T_ && act)
                     ? h_seq[((size_t)(s + 2) * B_ + b) * F_ + ct] : 0.f;
      float d = bd;
      const float* eb = ebuf[i & 1];
      #pragma unroll
      for (int k = 0; k < H_; ++k) d += wd[k] * eb[k];
      float fo = fmaxf(d, 0.f);
      float df = fo - h0;
      if (act) acc += df * df;
      h0 = h1;
      h1 = h2;
      __syncthreads();
    }
  }

  // deterministic block reduction: wave shfl-reduce, then thread 0 sums waves
  #pragma unroll
  for (int m = 32; m >= 1; m >>= 1) acc += __shfl_xor(acc, m);
  if (lane == 0) red[wave] = acc;
  __syncthreads();
  if (tid == 0) {
    partials[b] = red[0] + red[1] + red[2] + red[3] + red[4];
  }
}

// ---------------- K3: final deterministic reduction ----------------
__global__ __launch_bounds__(64) void k3_reduce(
    const float* __restrict__ partials, float* __restrict__ out)
{
  const int lane = threadIdx.x;
  float a = partials[lane] + partials[lane + 64];
  #pragma unroll
  for (int m = 32; m >= 1; m >>= 1) a += __shfl_xor(a, m);
  if (lane == 0) out[0] = a * (float)(1.0 / ((double)T_ * B_ * F_));
}

extern "C" void kernel_launch(void* const* d_in, const int* in_sizes, int n_in,
                              void* d_out, int out_size, void* d_ws, size_t ws_size,
                              hipStream_t stream) {
  const float* feats = (const float*)d_in[0];
  const float* e0    = (const float*)d_in[1];
  const float* W_ih  = (const float*)d_in[2];
  const float* W_hh  = (const float*)d_in[3];
  const float* b_ih  = (const float*)d_in[4];
  const float* b_hh  = (const float*)d_in[5];
  const float* W_dec = (const float*)d_in[6];
  const float* b_dec = (const float*)d_in[7];
  float* out = (float*)d_out;

  float* ws = (float*)d_ws;
  float* h_seq    = ws;                                    // T*B*F floats
  float* xgates   = ws + (size_t)T_ * B_ * F_;             // T*B*G floats
  float* partials = xgates + (size_t)T_ * B_ * G_;         // B floats

  hipLaunchKernelGGL(k1_pool_gates, dim3(T_), dim3(256), 0, stream,
                     feats, W_ih, b_ih, h_seq, xgates);
  hipLaunchKernelGGL(k2_scan, dim3(B_), dim3(320), 0, stream,
                     e0, W_hh, b_hh, W_dec, b_dec, h_seq, xgates, partials);
  hipLaunchKernelGGL(k3_reduce, dim3(1), dim3(64), 0, stream,
                     partials, out);
}

// Round 2
// 1057.688 us; speedup vs baseline: 1.1205x; 1.1205x over previous
//
#include <hip/hip_runtime.h>
#include <cstddef>

#define T_ 1024
#define B_ 128
#define F_ 243
#define H_ 20
#define G_ 60   // 3*H
#define R_ 512  // B*POOL
#define P_ 8    // xg prefetch depth in k2

// ---------------- K1: max-pool(4) + x_gates = h @ W_ih^T + b_ih ----------------
// One block per timestep t. W_ih staged in LDS (stride 244, col 243 zero-pad).
// xg is written B-MAJOR: xg[b][t][g] so k2's per-block stream is contiguous.
__global__ __launch_bounds__(256) void k1_pool_gates(
    const float* __restrict__ feats, const float* __restrict__ W_ih,
    const float* __restrict__ b_ih, float* __restrict__ h_seq,
    float* __restrict__ xg)
{
  __shared__ __align__(16) float wih[G_ * 244];   // 58560 B
  __shared__ __align__(16) float hb[4][244];      //  3904 B
  const int t = blockIdx.x;
  const int tid = threadIdx.x;
  const int wave = tid >> 6, lane = tid & 63;

  for (int i = tid; i < G_ * F_; i += 256) {
    int g = i / F_, f = i - g * F_;
    wih[g * 244 + f] = W_ih[i];
  }
  if (tid < G_) wih[tid * 244 + 243] = 0.f;
  if (tid < 4) hb[tid][243] = 0.f;

  float bi = (lane < G_) ? b_ih[lane] : 0.f;
  __syncthreads();

  const float* fbase = feats + (size_t)t * R_ * F_;

  for (int b0 = 0; b0 < B_; b0 += 4) {
    for (int i = tid; i < 4 * F_; i += 256) {
      int bb = i / F_, f = i - bb * F_;
      const float* p = fbase + (size_t)(b0 + bb) * 4 * F_ + f;
      float m = fmaxf(fmaxf(p[0], p[F_]), fmaxf(p[2 * F_], p[3 * F_]));
      hb[bb][f] = m;
      h_seq[((size_t)t * B_ + (b0 + bb)) * F_ + f] = m;
    }
    __syncthreads();
    if (lane < G_) {
      const int g = lane;
      float acc = 0.f;
      #pragma unroll 4
      for (int f = 0; f < 244; f += 4) {
        const float4 w4 = *(const float4*)&wih[g * 244 + f];
        const float4 a4 = *(const float4*)&hb[wave][f];
        acc += w4.x * a4.x + w4.y * a4.y + w4.z * a4.z + w4.w * a4.w;
      }
      xg[((size_t)(b0 + wave) * T_ + t) * G_ + g] = acc + bi;  // b-major
    }
    __syncthreads();
  }
}

// ---------------- K2: recurrence only ----------------
// One wave per batch row. No LDS, no barriers. Lane g<60 owns W_hh row g; full
// e vector replicated in every lane's registers via shfl broadcast. xg streamed
// from the block's private b-major slab with distance-8 rotating prefetch.
// e_seq ([B][T][H]) is aliased onto the HEAD of the block's own xg slab:
// write ptr 80*t stays strictly below the unread-xg ptr 240*(t+1) for all t,
// and the only truly overlapping pair (prologue xv[0] load vs t=0 store) is
// ordered by a register data dependence. Blocks touch only their own slab.
__global__ __launch_bounds__(64) void k2_recur(
    const float* __restrict__ e0, const float* __restrict__ W_hh,
    const float* __restrict__ b_hh, const float* __restrict__ xg,
    float* __restrict__ e_seq)
{
  const int b = blockIdx.x;
  const int lane = threadIdx.x;

  float w[H_];
  float bh = 0.f;
  if (lane < G_) {
    #pragma unroll
    for (int k = 0; k < H_; ++k) w[k] = W_hh[lane * H_ + k];
    bh = b_hh[lane];
  }
  float e[H_];
  #pragma unroll
  for (int k = 0; k < H_; ++k) e[k] = e0[b * H_ + k];
  float e_own = (lane < H_) ? e0[b * H_ + lane] : 0.f;

  const float* xgb = xg + (size_t)b * T_ * G_;      // this block's slab
  float* esb = e_seq + (size_t)b * T_ * H_;         // aliased slab head

  float xv[P_];
  #pragma unroll
  for (int j = 0; j < P_; ++j)
    xv[j] = (lane < G_) ? xgb[(size_t)j * G_ + lane] : 0.f;

  for (int t0 = 0; t0 < T_; t0 += P_) {
    #pragma unroll
    for (int j = 0; j < P_; ++j) {
      const int t = t0 + j;
      const float x = xv[j];
      if (t + P_ < T_)
        xv[j] = (lane < G_) ? xgb[(size_t)(t + P_) * G_ + lane] : 0.f;

      float h0 = bh, h1 = 0.f, h2 = 0.f, h3 = 0.f;
      #pragma unroll
      for (int k = 0; k < H_; k += 4) {
        h0 += w[k]     * e[k];
        h1 += w[k + 1] * e[k + 1];
        h2 += w[k + 2] * e[k + 2];
        h3 += w[k + 3] * e[k + 3];
      }
      const float hg = (h0 + h1) + (h2 + h3);

      const float hgz = __shfl(hg, lane + 20);
      const float hgn = __shfl(hg, lane + 40);
      const float xz  = __shfl(x,  lane + 20);
      const float xn  = __shfl(x,  lane + 40);

      const float r = 1.f / (1.f + __expf(-(x + hg)));
      const float z = 1.f / (1.f + __expf(-(xz + hgz)));
      const float a = xn + r * hgn;
      const float n = 1.f - 2.f / (__expf(2.f * a) + 1.f);  // tanh(a)
      const float enew = (1.f - z) * n + z * e_own;

      #pragma unroll
      for (int k = 0; k < H_; ++k) e[k] = __shfl(enew, k);
      e_own = enew;
      if (lane < H_) esb[(size_t)t * H_ + lane] = enew;
    }
  }
}

// ---------------- K4: decoder + per-row squared-error, fully parallel ----------------
// thread = output column f (W_dec row lives in 20 registers for all rows);
// block processes 128 consecutive (b,t) rows; e rows are 80B broadcast loads.
#define K4_ROWS 128
__global__ __launch_bounds__(256) void k4_decode(
    const float* __restrict__ W_dec, const float* __restrict__ b_dec,
    const float* __restrict__ h_seq, const float* __restrict__ e_seq,
    float* __restrict__ partials)
{
  __shared__ float red[4];
  const int tid = threadIdx.x;
  const int f = tid;
  const bool act = f < F_;
  const int lane = tid & 63, wave = tid >> 6;

  float wd[H_];
  float bd = 0.f;
  if (act) {
    #pragma unroll
    for (int k = 0; k < H_; ++k) wd[k] = W_dec[f * H_ + k];
    bd = b_dec[f];
  }

  float acc = 0.f;
  const size_t r0 = (size_t)blockIdx.x * K4_ROWS;
  for (int i = 0; i < K4_ROWS; ++i) {
    const size_t r = r0 + i;           // r = b*T + t  (e_seq is b-major)
    const int bb = (int)(r >> 10);     // r / T_
    const int tt = (int)(r & (T_ - 1));
    const float* ep = e_seq + r * H_;
    float d = bd;
    #pragma unroll
    for (int k = 0; k < H_; ++k) d += wd[k] * ep[k];
    const float fo = fmaxf(d, 0.f);
    if (act) {
      const float h = h_seq[((size_t)tt * B_ + bb) * F_ + f];
      const float df = fo - h;
      acc += df * df;
    }
  }

  #pragma unroll
  for (int m = 32; m >= 1; m >>= 1) acc += __shfl_xor(acc, m);
  if (lane == 0) red[wave] = acc;
  __syncthreads();
  if (tid == 0) partials[blockIdx.x] = red[0] + red[1] + red[2] + red[3];
}

// ---------------- K3: final deterministic reduction over 1024 partials ----------------
__global__ __launch_bounds__(64) void k3_reduce(
    const float* __restrict__ partials, float* __restrict__ out)
{
  const int lane = threadIdx.x;
  float a = 0.f;
  #pragma unroll
  for (int i = 0; i < 16; ++i) a += partials[i * 64 + lane];
  #pragma unroll
  for (int m = 32; m >= 1; m >>= 1) a += __shfl_xor(a, m);
  if (lane == 0) out[0] = a * (float)(1.0 / ((double)T_ * B_ * F_));
}

extern "C" void kernel_launch(void* const* d_in, const int* in_sizes, int n_in,
                              void* d_out, int out_size, void* d_ws, size_t ws_size,
                              hipStream_t stream) {
  const float* feats = (const float*)d_in[0];
  const float* e0    = (const float*)d_in[1];
  const float* W_ih  = (const float*)d_in[2];
  const float* W_hh  = (const float*)d_in[3];
  const float* b_ih  = (const float*)d_in[4];
  const float* b_hh  = (const float*)d_in[5];
  const float* W_dec = (const float*)d_in[6];
  const float* b_dec = (const float*)d_in[7];
  float* out = (float*)d_out;

  float* ws = (float*)d_ws;
  float* h_seq    = ws;                                    // T*B*F floats
  float* xgates   = ws + (size_t)T_ * B_ * F_;             // B*T*G floats (b-major)
  float* e_seq    = xgates;                                // aliased: [B][T][H] head of each slab
  float* partials = xgates + (size_t)T_ * B_ * G_;         // 1024 floats

  hipLaunchKernelGGL(k1_pool_gates, dim3(T_), dim3(256), 0, stream,
                     feats, W_ih, b_ih, h_seq, xgates);
  hipLaunchKernelGGL(k2_recur, dim3(B_), dim3(64), 0, stream,
                     e0, W_hh, b_hh, xgates, e_seq);
  hipLaunchKernelGGL(k4_decode, dim3((T_ * B_) / K4_ROWS), dim3(256), 0, stream,
                     W_dec, b_dec, h_seq, e_seq, partials);
  hipLaunchKernelGGL(k3_reduce, dim3(1), dim3(64), 0, stream,
                     partials, out);
}

// Round 3
// 661.348 us; speedup vs baseline: 1.7921x; 1.5993x over previous
//
#include <hip/hip_runtime.h>
#include <cstddef>

#define T_ 1024
#define B_ 128
#define F_ 243
#define H_ 20
#define G_ 60   // 3*H
#define R_ 512  // B*POOL
#define P_ 8    // xg prefetch depth in k2

__device__ __forceinline__ float rdlane(float v, int l) {
  return __int_as_float(__builtin_amdgcn_readlane(__float_as_int(v), l));
}

// ---------------- K1: max-pool(4) + x_gates = h @ W_ih^T + b_ih ----------------
// One block per timestep t. W_ih staged in LDS (stride 244, col 243 zero-pad).
// Lane mapping for the dot: lane = 16*bb + gi, gate g = 16*wave + gi. Each
// W_ih row is read by one lane per wave (not 4 waves x 60 lanes), and hb rows
// are 16-way broadcast -> ~3.7x less LDS read traffic than lane=gate.
// Outputs: h_seq b-major [B][T][F], xg b-major [B][T][G].
__global__ __launch_bounds__(256) void k1_pool_gates(
    const float* __restrict__ feats, const float* __restrict__ W_ih,
    const float* __restrict__ b_ih, float* __restrict__ h_seq,
    float* __restrict__ xg)
{
  __shared__ __align__(16) float wih[G_ * 244];   // 58560 B
  __shared__ __align__(16) float hb[4][244];      //  3904 B
  const int t = blockIdx.x;
  const int tid = threadIdx.x;
  const int wave = tid >> 6, lane = tid & 63;
  const int bb = lane >> 4, gi = lane & 15;
  const int g = wave * 16 + gi;          // 0..63
  const bool gok = g < G_;
  const int gc = gok ? g : 0;            // clamped row for idle lanes

  for (int i = tid; i < G_ * F_; i += 256) {
    int gg = i / F_, f = i - gg * F_;
    wih[gg * 244 + f] = W_ih[i];
  }
  if (tid < G_) wih[tid * 244 + 243] = 0.f;
  if (tid < 4) hb[tid][243] = 0.f;
  const float bi = gok ? b_ih[g] : 0.f;
  __syncthreads();

  const float* fbase = feats + (size_t)t * R_ * F_;

  for (int b0 = 0; b0 < B_; b0 += 4) {
    for (int i = tid; i < 4 * F_; i += 256) {
      int r = i / F_, f = i - r * F_;
      const float* p = fbase + (size_t)(b0 + r) * 4 * F_ + f;
      float m = fmaxf(fmaxf(p[0], p[F_]), fmaxf(p[2 * F_], p[3 * F_]));
      hb[r][f] = m;
      h_seq[((size_t)(b0 + r) * T_ + t) * F_ + f] = m;   // b-major
    }
    __syncthreads();
    {
      float a0 = 0.f, a1 = 0.f;
      const float* wrow = &wih[gc * 244];
      const float* hrow = &hb[bb][0];
      #pragma unroll 5
      for (int f = 0; f < 240; f += 8) {
        const float4 w4 = *(const float4*)&wrow[f];
        const float4 x4 = *(const float4*)&hrow[f];
        a0 += w4.x * x4.x + w4.y * x4.y + w4.z * x4.z + w4.w * x4.w;
        const float4 w5 = *(const float4*)&wrow[f + 4];
        const float4 x5 = *(const float4*)&hrow[f + 4];
        a1 += w5.x * x5.x + w5.y * x5.y + w5.z * x5.z + w5.w * x5.w;
      }
      {
        const float4 w4 = *(const float4*)&wrow[240];
        const float4 x4 = *(const float4*)&hrow[240];   // [243] is zero pad
        a0 += w4.x * x4.x + w4.y * x4.y + w4.z * x4.z + w4.w * x4.w;
      }
      if (gok)
        xg[((size_t)(b0 + bb) * T_ + t) * G_ + g] = a0 + a1 + bi;  // b-major
    }
    __syncthreads();
  }
}

// ---------------- K2: recurrence only, zero cross-lane DS ops ----------------
// One wave per batch row. Lane j<20 owns the full gate triple (r_j,z_j,n_j):
// W_hh rows j, j+20, j+40 in VGPRs. The shared e vector lives in SGPRs,
// refreshed each step by 20 v_readlane from enew (no ds_bpermute anywhere).
// Idle lanes (>=20) run the same code on clamped indices; results never read.
// e_seq [B][T][H] aliases the head of this block's own b-major xg slab:
// write ptr 80*t stays below the prefetch read ptr 240*(t+P_).
__global__ __launch_bounds__(64) void k2_recur(
    const float* __restrict__ e0, const float* __restrict__ W_hh,
    const float* __restrict__ b_hh, const float* __restrict__ xg,
    float* __restrict__ e_seq)
{
  const int b = blockIdx.x;
  const int lane = threadIdx.x;
  const bool own = lane < H_;
  const int j0 = own ? lane : 0;

  float wr[H_], wz[H_], wn[H_];
  #pragma unroll
  for (int k = 0; k < H_; ++k) {
    wr[k] = W_hh[j0 * H_ + k];
    wz[k] = W_hh[(j0 + 20) * H_ + k];
    wn[k] = W_hh[(j0 + 40) * H_ + k];
  }
  const float bhr = b_hh[j0], bhz = b_hh[j0 + 20], bhn = b_hh[j0 + 40];

  float e_own = e0[b * H_ + j0];
  float es[H_];
  #pragma unroll
  for (int k = 0; k < H_; ++k) es[k] = rdlane(e_own, k);

  const float* xgb = xg + (size_t)b * T_ * G_;
  float* esb = e_seq + (size_t)b * T_ * H_;

  float xr[P_], xz[P_], xn[P_];
  #pragma unroll
  for (int j = 0; j < P_; ++j) {
    xr[j] = xgb[(size_t)j * G_ + j0];
    xz[j] = xgb[(size_t)j * G_ + j0 + 20];
    xn[j] = xgb[(size_t)j * G_ + j0 + 40];
  }

#define STEP(j, RELOAD)                                                    \
  {                                                                        \
    const int t = t0 + (j);                                                \
    const float xrv = xr[j], xzv = xz[j], xnv = xn[j];                     \
    if (RELOAD) {                                                          \
      const float* xp = xgb + (size_t)(t + P_) * G_;                       \
      xr[j] = xp[j0]; xz[j] = xp[j0 + 20]; xn[j] = xp[j0 + 40];            \
    }                                                                      \
    float r0 = bhr, r1 = 0.f, z0 = bhz, z1 = 0.f, n0 = bhn, n1 = 0.f;      \
    _Pragma("unroll")                                                      \
    for (int k = 0; k < H_; k += 2) {                                      \
      r0 += wr[k] * es[k];     r1 += wr[k + 1] * es[k + 1];                \
      z0 += wz[k] * es[k];     z1 += wz[k + 1] * es[k + 1];                \
      n0 += wn[k] * es[k];     n1 += wn[k + 1] * es[k + 1];                \
    }                                                                      \
    const float hr = r0 + r1, hz = z0 + z1, hn = n0 + n1;                  \
    const float rg = 1.f / (1.f + __expf(-(xrv + hr)));                    \
    const float zg = 1.f / (1.f + __expf(-(xzv + hz)));                    \
    const float aa = xnv + rg * hn;                                        \
    const float ng = 1.f - 2.f / (__expf(2.f * aa) + 1.f);                 \
    const float enew = (1.f - zg) * ng + zg * e_own;                       \
    if (own) esb[(size_t)t * H_ + lane] = enew;                            \
    e_own = enew;                                                          \
    _Pragma("unroll")                                                      \
    for (int k = 0; k < H_; ++k) es[k] = rdlane(enew, k);                  \
  }

  for (int t0 = 0; t0 < T_ - P_; t0 += P_) {
    STEP(0, true) STEP(1, true) STEP(2, true) STEP(3, true)
    STEP(4, true) STEP(5, true) STEP(6, true) STEP(7, true)
  }
  {
    const int t0 = T_ - P_;
    STEP(0, false) STEP(1, false) STEP(2, false) STEP(3, false)
    STEP(4, false) STEP(5, false) STEP(6, false) STEP(7, false)
  }
#undef STEP
}

// ---------------- K4: decoder + per-row squared-error, fully parallel ----------------
// thread = output column f; block processes 128 consecutive (b,t) rows.
// h_seq and e_seq are both b-major -> each block streams contiguous memory.
#define K4_ROWS 128
__global__ __launch_bounds__(256) void k4_decode(
    const float* __restrict__ W_dec, const float* __restrict__ b_dec,
    const float* __restrict__ h_seq, const float* __restrict__ e_seq,
    float* __restrict__ partials)
{
  __shared__ float red[4];
  const int tid = threadIdx.x;
  const int f = tid;
  const bool act = f < F_;
  const int lane = tid & 63, wave = tid >> 6;

  float wd[H_];
  float bd = 0.f;
  if (act) {
    #pragma unroll
    for (int k = 0; k < H_; ++k) wd[k] = W_dec[f * H_ + k];
    bd = b_dec[f];
  }

  float acc = 0.f;
  const size_t r0 = (size_t)blockIdx.x * K4_ROWS;
  for (int i = 0; i < K4_ROWS; ++i) {
    const size_t r = r0 + i;           // r = b*T + t (both buffers b-major)
    const float* ep = e_seq + r * H_;
    float d = bd;
    #pragma unroll
    for (int k = 0; k < H_; ++k) d += wd[k] * ep[k];
    const float fo = fmaxf(d, 0.f);
    if (act) {
      const float h = h_seq[r * F_ + f];
      const float df = fo - h;
      acc += df * df;
    }
  }

  #pragma unroll
  for (int m = 32; m >= 1; m >>= 1) acc += __shfl_xor(acc, m);
  if (lane == 0) red[wave] = acc;
  __syncthreads();
  if (tid == 0) partials[blockIdx.x] = red[0] + red[1] + red[2] + red[3];
}

// ---------------- K3: final deterministic reduction over 1024 partials ----------------
__global__ __launch_bounds__(64) void k3_reduce(
    const float* __restrict__ partials, float* __restrict__ out)
{
  const int lane = threadIdx.x;
  float a = 0.f;
  #pragma unroll
  for (int i = 0; i < 16; ++i) a += partials[i * 64 + lane];
  #pragma unroll
  for (int m = 32; m >= 1; m >>= 1) a += __shfl_xor(a, m);
  if (lane == 0) out[0] = a * (float)(1.0 / ((double)T_ * B_ * F_));
}

extern "C" void kernel_launch(void* const* d_in, const int* in_sizes, int n_in,
                              void* d_out, int out_size, void* d_ws, size_t ws_size,
                              hipStream_t stream) {
  const float* feats = (const float*)d_in[0];
  const float* e0    = (const float*)d_in[1];
  const float* W_ih  = (const float*)d_in[2];
  const float* W_hh  = (const float*)d_in[3];
  const float* b_ih  = (const float*)d_in[4];
  const float* b_hh  = (const float*)d_in[5];
  const float* W_dec = (const float*)d_in[6];
  const float* b_dec = (const float*)d_in[7];
  float* out = (float*)d_out;

  float* ws = (float*)d_ws;
  float* h_seq    = ws;                                    // B*T*F floats (b-major)
  float* xgates   = ws + (size_t)T_ * B_ * F_;             // B*T*G floats (b-major)
  float* e_seq    = xgates;                                // aliased slab heads [B][T][H]
  float* partials = xgates + (size_t)T_ * B_ * G_;         // 1024 floats

  hipLaunchKernelGGL(k1_pool_gates, dim3(T_), dim3(256), 0, stream,
                     feats, W_ih, b_ih, h_seq, xgates);
  hipLaunchKernelGGL(k2_recur, dim3(B_), dim3(64), 0, stream,
                     e0, W_hh, b_hh, xgates, e_seq);
  hipLaunchKernelGGL(k4_decode, dim3((T_ * B_) / K4_ROWS), dim3(256), 0, stream,
                     W_dec, b_dec, h_seq, e_seq, partials);
  hipLaunchKernelGGL(k3_reduce, dim3(1), dim3(64), 0, stream,
                     partials, out);
}

// Round 4
// 622.308 us; speedup vs baseline: 1.9045x; 1.0627x over previous
//
#include <hip/hip_runtime.h>
#include <cstddef>

#define T_ 1024
#define B_ 128
#define F_ 243
#define H_ 20
#define G_ 60   // 3*H
#define R_ 512  // B*POOL
#define P_ 8    // xg prefetch depth in k2 (also the e-store shift)

__device__ __forceinline__ float rdlane(float v, int l) {
  return __int_as_float(__builtin_amdgcn_readlane(__float_as_int(v), l));
}

// ---------------- K1: fused max-pool(4) + tall GEMM  xg = pool(feats) @ W_ih^T + b_ih ---------
// Block = (b, 128 consecutive t). 4 f-chunks of 64 (last zero-padded past 243).
// Staging pools feats directly into the LDS A-tile (h_seq written as byproduct).
// Thread tile: 8 rows x 4 gates, 256 threads = 16 row-groups x 16 gate-cols.
// A-tile XOR swizzle: 16B-unit index f4 stored at f4 ^ (row>>3) so a wave's 4
// row-groups (rows i, i+8, i+16, i+24 within its quarter) hit disjoint bank
// quads on ds_read_b128 (plain stride-64 would be 4-way conflicted).
__global__ __launch_bounds__(256) void k1_fused(
    const float* __restrict__ feats, const float* __restrict__ W_ih,
    const float* __restrict__ b_ih, float* __restrict__ h_seq,
    float* __restrict__ xg)
{
  __shared__ __align__(16) float As[128 * 64];   // 32 KB
  __shared__ __align__(16) float Ws[64 * 60];    // 15.4 KB
  const int bid = blockIdx.x;
  const int b = bid >> 3;
  const int t0 = (bid & 7) << 7;
  const int tid = threadIdx.x;
  const int rg = tid >> 4;                 // 0..15 row group (8 rows each)
  const int gcol = tid & 15;               // 0..15 gate col (4 gates each)
  const int gc4 = (gcol < 15) ? gcol * 4 : 56;   // clamp col 15 (dup of 14)
  const float4 bi4 = *(const float4*)&b_ih[gc4];

  float acc[8][4];
  #pragma unroll
  for (int i = 0; i < 8; ++i) {
    #pragma unroll
    for (int j = 0; j < 4; ++j) acc[i][j] = 0.f;
  }

  for (int fc = 0; fc < F_; fc += 64) {
    __syncthreads();   // previous chunk's reads done before restaging
    // ---- stage pooled A (and write h_seq) ----
    #pragma unroll 4
    for (int i = tid; i < 128 * 64; i += 256) {
      const int row = i >> 6;          // t offset 0..127
      const int j = i & 63;
      const int col = fc + j;
      float v = 0.f;
      if (col < F_) {
        const float* p = feats + ((size_t)(t0 + row) * R_ + (b << 2)) * F_ + col;
        v = fmaxf(fmaxf(p[0], p[F_]), fmaxf(p[2 * F_], p[3 * F_]));
        h_seq[((size_t)b * T_ + t0 + row) * F_ + col] = v;
      }
      As[(row << 6) + ((((j >> 2) ^ (row >> 3)) << 2) | (j & 3))] = v;
    }
    // ---- stage W chunk, f-major [64][60] ----
    for (int i = tid; i < 64 * 60; i += 256) {
      const int fo = i & 63;
      const int g = i >> 6;
      const int col = fc + fo;
      Ws[fo * 60 + g] = (col < F_) ? W_ih[g * F_ + col] : 0.f;
    }
    __syncthreads();
    // ---- register-tiled GEMM: 16 f4-steps, 128 FMA each ----
    #pragma unroll
    for (int fj = 0; fj < 16; ++fj) {
      const float4 w0 = *(const float4*)&Ws[(fj * 4 + 0) * 60 + gc4];
      const float4 w1 = *(const float4*)&Ws[(fj * 4 + 1) * 60 + gc4];
      const float4 w2 = *(const float4*)&Ws[(fj * 4 + 2) * 60 + gc4];
      const float4 w3 = *(const float4*)&Ws[(fj * 4 + 3) * 60 + gc4];
      #pragma unroll
      for (int i = 0; i < 8; ++i) {
        const int row = (rg << 3) + i;
        const float4 a = *(const float4*)&As[(row << 6) + ((fj ^ rg) << 2)];
        acc[i][0] = fmaf(a.x, w0.x, fmaf(a.y, w1.x, fmaf(a.z, w2.x, fmaf(a.w, w3.x, acc[i][0]))));
        acc[i][1] = fmaf(a.x, w0.y, fmaf(a.y, w1.y, fmaf(a.z, w2.y, fmaf(a.w, w3.y, acc[i][1]))));
        acc[i][2] = fmaf(a.x, w0.z, fmaf(a.y, w1.z, fmaf(a.z, w2.z, fmaf(a.w, w3.z, acc[i][2]))));
        acc[i][3] = fmaf(a.x, w0.w, fmaf(a.y, w1.w, fmaf(a.z, w2.w, fmaf(a.w, w3.w, acc[i][3]))));
      }
    }
  }
  // ---- epilogue: add bias, store xg b-major ----
  if (gcol < 15) {
    #pragma unroll
    for (int i = 0; i < 8; ++i) {
      const int row = (rg << 3) + i;
      float4 o;
      o.x = acc[i][0] + bi4.x;  o.y = acc[i][1] + bi4.y;
      o.z = acc[i][2] + bi4.z;  o.w = acc[i][3] + bi4.w;
      *(float4*)&xg[((size_t)b * T_ + t0 + row) * G_ + gcol * 4] = o;
    }
  }
}

// ---------------- K2: recurrence only, zero cross-lane DS ops ----------------
// One wave per batch row. Lane j<20 owns the gate triple (r_j,z_j,n_j); the
// shared e vector lives in SGPRs via v_readlane. e(t) is stored into THIS
// block's own xg slab at packed offset (t-8)*20 (that region's loads were
// issued and consumed >=8 steps earlier by the same lanes); t<8 goes to ehead.
// No cross-block aliasing -> dispatch-order independent (G16).
// NOTE: xg / e_store intentionally NOT __restrict__ (they alias).
__global__ __launch_bounds__(64) void k2_recur(
    const float* __restrict__ e0, const float* __restrict__ W_hh,
    const float* __restrict__ b_hh, const float* xg,
    float* e_store, float* __restrict__ ehead)
{
  const int b = blockIdx.x;
  const int lane = threadIdx.x;
  const bool own = lane < H_;
  const int j0 = own ? lane : 0;

  float wr[H_], wz[H_], wn[H_];
  #pragma unroll
  for (int k = 0; k < H_; ++k) {
    wr[k] = W_hh[j0 * H_ + k];
    wz[k] = W_hh[(j0 + 20) * H_ + k];
    wn[k] = W_hh[(j0 + 40) * H_ + k];
  }
  const float bhr = b_hh[j0], bhz = b_hh[j0 + 20], bhn = b_hh[j0 + 40];

  float e_own = e0[b * H_ + j0];
  float es[H_];
  #pragma unroll
  for (int k = 0; k < H_; ++k) es[k] = rdlane(e_own, k);

  const float* xgb = xg + (size_t)b * T_ * G_;
  float* xslab = e_store + (size_t)b * T_ * G_;   // packed e at (t-8)*20
  float* ehb = ehead + b * (P_ * H_);

  float xr[P_], xz[P_], xn[P_];
  #pragma unroll
  for (int j = 0; j < P_; ++j) {
    xr[j] = xgb[(size_t)j * G_ + j0];
    xz[j] = xgb[(size_t)j * G_ + j0 + 20];
    xn[j] = xgb[(size_t)j * G_ + j0 + 40];
  }

#define STEP(j, RELOAD)                                                    \
  {                                                                        \
    const int t = t0 + (j);                                                \
    const float xrv = xr[j], xzv = xz[j], xnv = xn[j];                     \
    if (RELOAD) {                                                          \
      const float* xp = xgb + (size_t)(t + P_) * G_;                       \
      xr[j] = xp[j0]; xz[j] = xp[j0 + 20]; xn[j] = xp[j0 + 40];            \
    }                                                                      \
    float r0 = bhr, r1 = 0.f, z0 = bhz, z1 = 0.f, n0 = bhn, n1 = 0.f;      \
    _Pragma("unroll")                                                      \
    for (int k = 0; k < H_; k += 2) {                                      \
      r0 += wr[k] * es[k];     r1 += wr[k + 1] * es[k + 1];                \
      z0 += wz[k] * es[k];     z1 += wz[k + 1] * es[k + 1];                \
      n0 += wn[k] * es[k];     n1 += wn[k + 1] * es[k + 1];                \
    }                                                                      \
    const float hr = r0 + r1, hz = z0 + z1, hn = n0 + n1;                  \
    const float rg = 1.f / (1.f + __expf(-(xrv + hr)));                    \
    const float zg = 1.f / (1.f + __expf(-(xzv + hz)));                    \
    const float aa = xnv + rg * hn;                                        \
    const float ng = 1.f - 2.f / (__expf(2.f * aa) + 1.f);                 \
    const float enew = (1.f - zg) * ng + zg * e_own;                       \
    if (own) {                                                             \
      float* dst = (t >= P_) ? (xslab + (size_t)(t - P_) * H_ + lane)      \
                             : (ehb + t * H_ + lane);                      \
      *dst = enew;                                                         \
    }                                                                      \
    e_own = enew;                                                          \
    _Pragma("unroll")                                                      \
    for (int k = 0; k < H_; ++k) es[k] = rdlane(enew, k);                  \
  }

  for (int t0 = 0; t0 < T_ - P_; t0 += P_) {
    STEP(0, true) STEP(1, true) STEP(2, true) STEP(3, true)
    STEP(4, true) STEP(5, true) STEP(6, true) STEP(7, true)
  }
  {
    const int t0 = T_ - P_;
    STEP(0, false) STEP(1, false) STEP(2, false) STEP(3, false)
    STEP(4, false) STEP(5, false) STEP(6, false) STEP(7, false)
  }
#undef STEP
}

// ---------------- K4: decoder + squared-error ----------------
// Block = 128 consecutive (b,t) rows (all one b). e rows staged to LDS once
// (kills the per-row uniform-load latency chain), then read as float2
// broadcasts. thread = output column f with W_dec row in registers.
#define K4_ROWS 128
__global__ __launch_bounds__(256) void k4_decode(
    const float* __restrict__ W_dec, const float* __restrict__ b_dec,
    const float* __restrict__ h_seq, const float* __restrict__ e_store,
    const float* __restrict__ ehead, float* __restrict__ partials)
{
  __shared__ float elds[K4_ROWS * H_];   // 10 KB
  __shared__ float red[4];
  const int tid = threadIdx.x;
  const int f = tid;
  const bool act = f < F_;
  const int lane = tid & 63, wave = tid >> 6;
  const size_t r0 = (size_t)blockIdx.x * K4_ROWS;
  const int b = (int)(r0 >> 10);
  const int t0 = (int)(r0 & (T_ - 1));
  const float* xslab = e_store + (size_t)b * T_ * G_;
  const float* ehb = ehead + b * (P_ * H_);

  for (int i = tid; i < K4_ROWS * H_; i += 256) {
    const int trow = i / H_;
    const int c = i - trow * H_;
    const int t = t0 + trow;
    elds[i] = (t >= P_) ? xslab[(size_t)(t - P_) * H_ + c] : ehb[t * H_ + c];
  }

  float wd[H_];
  float bd = 0.f;
  if (act) {
    #pragma unroll
    for (int k = 0; k < H_; ++k) wd[k] = W_dec[f * H_ + k];
    bd = b_dec[f];
  }
  __syncthreads();

  float acc = 0.f;
  #pragma unroll 2
  for (int i = 0; i < K4_ROWS; ++i) {
    const float2* ep = (const float2*)&elds[i * H_];
    float d = bd;
    #pragma unroll
    for (int k = 0; k < 10; ++k) {
      const float2 e2 = ep[k];
      d = fmaf(wd[2 * k], e2.x, fmaf(wd[2 * k + 1], e2.y, d));
    }
    const float fo = fmaxf(d, 0.f);
    if (act) {
      const float h = h_seq[(r0 + i) * F_ + f];
      const float df = fo - h;
      acc = fmaf(df, df, acc);
    }
  }

  #pragma unroll
  for (int m = 32; m >= 1; m >>= 1) acc += __shfl_xor(acc, m);
  if (lane == 0) red[wave] = acc;
  __syncthreads();
  if (tid == 0) partials[blockIdx.x] = red[0] + red[1] + red[2] + red[3];
}

// ---------------- K3: final deterministic reduction over 1024 partials ----------------
__global__ __launch_bounds__(64) void k3_reduce(
    const float* __restrict__ partials, float* __restrict__ out)
{
  const int lane = threadIdx.x;
  float a = 0.f;
  #pragma unroll
  for (int i = 0; i < 16; ++i) a += partials[i * 64 + lane];
  #pragma unroll
  for (int m = 32; m >= 1; m >>= 1) a += __shfl_xor(a, m);
  if (lane == 0) out[0] = a * (float)(1.0 / ((double)T_ * B_ * F_));
}

extern "C" void kernel_launch(void* const* d_in, const int* in_sizes, int n_in,
                              void* d_out, int out_size, void* d_ws, size_t ws_size,
                              hipStream_t stream) {
  const float* feats = (const float*)d_in[0];
  const float* e0    = (const float*)d_in[1];
  const float* W_ih  = (const float*)d_in[2];
  const float* W_hh  = (const float*)d_in[3];
  const float* b_ih  = (const float*)d_in[4];
  const float* b_hh  = (const float*)d_in[5];
  const float* W_dec = (const float*)d_in[6];
  const float* b_dec = (const float*)d_in[7];
  float* out = (float*)d_out;

  float* ws = (float*)d_ws;
  float* h_seq    = ws;                                    // B*T*F floats (b-major)
  float* xgates   = ws + (size_t)T_ * B_ * F_;             // B*T*G floats (b-major)
  float* partials = xgates + (size_t)T_ * B_ * G_;         // 1024 floats
  float* ehead    = partials + 1024;                       // B*8*H floats (e for t<8)

  hipLaunchKernelGGL(k1_fused, dim3(B_ * 8), dim3(256), 0, stream,
                     feats, W_ih, b_ih, h_seq, xgates);
  hipLaunchKernelGGL(k2_recur, dim3(B_), dim3(64), 0, stream,
                     e0, W_hh, b_hh, xgates, xgates, ehead);
  hipLaunchKernelGGL(k4_decode, dim3((T_ * B_) / K4_ROWS), dim3(256), 0, stream,
                     W_dec, b_dec, h_seq, xgates, ehead, partials);
  hipLaunchKernelGGL(k3_reduce, dim3(1), dim3(64), 0, stream,
                     partials, out);
}